// Round 4
// baseline (247.481 us; speedup 1.0000x reference)
//
#include <hip/hip_runtime.h>

typedef unsigned short u16;
typedef __bf16 bf16x8 __attribute__((ext_vector_type(8)));
typedef float f32x4 __attribute__((ext_vector_type(4)));

#define Bn 4
#define Sn 2048
#define Dn 1024
#define Hn 16
#define HDn 64

__device__ inline u16 f2bf(float f) {
  unsigned u = __builtin_bit_cast(unsigned, f);
  u += 0x7fffu + ((u >> 16) & 1u);
  return (u16)(u >> 16);
}

// async global->LDS DMA, 16B/lane; LDS dest = wave base + lane*16 [m97]
__device__ __forceinline__ void gl2lds16(const u16* g, u16* l) {
  __builtin_amdgcn_global_load_lds(
      (const __attribute__((address_space(1))) unsigned int*)g,
      (__attribute__((address_space(3))) unsigned int*)l, 16, 0, 0);
}

__device__ __forceinline__ float fexp2(float x) {
  return __builtin_amdgcn_exp2f(x);
}

// pack two f32 -> two bf16 (truncating) in one v_perm
__device__ __forceinline__ unsigned pk_bf_trunc(float lo, float hi) {
  return __builtin_amdgcn_perm(__builtin_bit_cast(unsigned, hi),
                               __builtin_bit_cast(unsigned, lo), 0x07060302u);
}

// ---- elementwise fp32 -> bf16 convert (x) ----
__global__ __launch_bounds__(256) void cvt4(const float* __restrict__ in,
                                            u16* __restrict__ out, int n4) {
  int i = blockIdx.x * 256 + threadIdx.x;
  if (i < n4) {
    float4 v = ((const float4*)in)[i];
    ushort4 o;
    o.x = f2bf(v.x); o.y = f2bf(v.y); o.z = f2bf(v.z); o.w = f2bf(v.w);
    ((ushort4*)out)[i] = o;
  }
}

// ---- transpose + convert 4 weights in one launch: out[z][n][k] = in_z[k][n] ----
__global__ __launch_bounds__(256) void tcvt4(const float* __restrict__ w0,
                                             const float* __restrict__ w1,
                                             const float* __restrict__ w2,
                                             const float* __restrict__ w3,
                                             u16* __restrict__ out) {
  __shared__ u16 tile[32][33];
  const float* in = (blockIdx.z == 0) ? w0 : (blockIdx.z == 1) ? w1
                   : (blockIdx.z == 2) ? w2 : w3;
  u16* dst = out + (size_t)blockIdx.z * Dn * Dn;
  int bx = blockIdx.x * 32;
  int by = blockIdx.y * 32;
  int tx = threadIdx.x & 31;
  int ty = threadIdx.x >> 5;
#pragma unroll
  for (int r = 0; r < 32; r += 8)
    tile[ty + r][tx] = f2bf(in[(size_t)(by + ty + r) * Dn + bx + tx]);
  __syncthreads();
#pragma unroll
  for (int r = 0; r < 32; r += 8)
    dst[(size_t)(bx + ty + r) * Dn + by + tx] = tile[tx][ty + r];
}

// ==== fused QKV gemm, 128x256 tile, BK=64, 8-wave, TRIPLE-buffer ====
// M=8192, N=3072 (Q|K|V), K=1024. 512 threads = 8 waves in 2(M) x 4(N).
// Per-wave output 64x64 (acc[4][4]). Grid 768 blocks = 64 Mt x 12 Nt =
// EXACTLY 3 rounds of 256 CUs (perfect balance; fixes R2's 2x-makespan tail).
// LDS: 3 bufs x 3 regions x 16KB = 144KB -> 1 block/CU.
//   rgA (S[b][0]): A rows 0..127
//   rgB1 (S[b][1]): B rows {wc*64+0..31}  (frags ni=0,1)
//   rgB2 (S[b][2]): B rows {wc*64+32..63} (frags ni=2,3)
// 2 phases per K-tile: P0 reads all B (8 frags, held in regs) + A-half0
// (4 reads) -> 16 MFMA; P1 reads A-half1 (4) -> 16 MFMA. 16 reads / 32 MFMA.
// Triple-buffer staging: tile t stages tile t+2 (P0: B1+A = 4 loads,
// P1: B2 = 2 loads). Leads: B1/A 3 phases, B2 2 phases (>= HBM latency).
// ONE wait per tile: vmcnt(6) at P1 (12 outstanding; oldest 6 = tile T+1's
// loads retire; 6 stay in flight -- m201/T4 discipline, never drains).
// vmcnt(0) only at T=14. Write-after-read on buf (T+2)%3 fenced by tile
// T-1 P1's lgkmcnt(0)+barrier2 preceding the stg issue.
// LDS swizzle: physical = logical ^ ((row bits1-3)<<4); gl2lds dest linear,
// global source inverse-swizzled (rule #21); ds_read applies the same
// involution -> bank-conflict-free (verified 0 in R1/R2).
__global__ __launch_bounds__(512, 2) void gemm_qkv(const u16* __restrict__ A,
                                                   const u16* __restrict__ Bt,
                                                   u16* __restrict__ qkb,
                                                   u16* __restrict__ vt,
                                                   float qscale) {
  __shared__ __attribute__((aligned(16))) u16 S[3][3][8192];  // 144 KB

  const int tid = threadIdx.x;
  const int lane = tid & 63;
  const int lcol = lane & 15;
  const int quad = lane >> 4;
  const int wave = tid >> 6;
  const int wr = wave >> 2;  // 0..1 (M)
  const int wc = wave & 3;   // 0..3 (N)

  // XCD swizzle: xcd = bid&7 owns M-tiles xcd*8..+7 across all 12 N-tiles;
  // within XCD iterate mt-major -> A chunk (2MB) + current B panels L2-fit.
  const int bid = blockIdx.x;
  const int idx = bid >> 3;                       // 0..95
  const int bm = (((bid & 7) << 3) + (idx & 7)) * 128;  // M tile 0..63
  const int bn = (idx >> 3) * 256;                      // N tile 0..11

  // --- staging source pointers: 3 regions x 2 chunks (8KB) per thread ---
  const u16* srcp[3][2];
#pragma unroll
  for (int rg = 0; rg < 3; rg++) {
#pragma unroll
    for (int j = 0; j < 2; j++) {
      int o = j * 8192 + tid * 16;            // physical byte offset in region
      int l = o ^ (((o >> 8) & 7) << 4);      // logical byte offset (involution)
      int rho = l >> 7;                       // local row 0..127
      int c2 = (l >> 1) & 63;                 // u16 col 0..63
      int gr;
      if (rg == 0)      gr = bm + rho;
      else if (rg == 1) gr = bn + ((rho >> 5) << 6) + (rho & 31);
      else              gr = bn + ((rho >> 5) << 6) + 32 + (rho & 31);
      const u16* base = (rg == 0) ? A : Bt;
      srcp[rg][j] = base + (size_t)gr * Dn + c2;
    }
  }

  auto stg = [&](int rg, int buf, int tile) {
    if (tile >= 16) return;  // tail guard (tiles 16,17)
    const int k0 = tile << 6;
    u16* d = &S[buf][rg][tid * 8];
    gl2lds16(srcp[rg][0] + k0, d);
    gl2lds16(srcp[rg][1] + k0, d + 4096);
  };

  f32x4 acc[4][4];
#pragma unroll
  for (int i = 0; i < 4; i++)
#pragma unroll
    for (int j = 0; j < 4; j++) acc[i][j] = (f32x4){0.f, 0.f, 0.f, 0.f};

  // ds_read swizzled column-byte offsets (row bits1-3 == lcol bits1-3)
  const int SW = (lcol & 14) << 3;
  const int cs0 = (quad * 16) ^ SW;         // k-step 0 (cols 0-31)
  const int cs1 = (64 + quad * 16) ^ SW;    // k-step 1 (cols 32-63)

  bf16x8 bk0[4], bk1[4];  // B frags, both k-steps, held across the K-tile

#define MFMA16(a, b, c) __builtin_amdgcn_mfma_f32_16x16x32_bf16(a, b, c, 0, 0, 0)

// A frag: half Q (0..1), F = frag-in-half (0..1), K = k-step
#define ARD(D, Q, F, K)                                                      \
  (*(const bf16x8*)((const char*)&S[D][0][0] +                               \
      ((wr * 64 + (Q) * 32 + (F) * 16 + lcol) * 128 + ((K) ? cs1 : cs0))))
// B frag: NI = N-frag (0..3), K = k-step
#define BRD(D, NI, K)                                                        \
  (*(const bf16x8*)((const char*)&S[D][1 + ((NI) >> 1)][0] +                 \
      ((wc * 32 + ((NI) & 1) * 16 + lcol) * 128 + ((K) ? cs1 : cs0))))

#define PHASE(D, Q, DO_B, STG_STMT, WAIT_STMT)                               \
  {                                                                          \
    bf16x8 a00 = ARD(D, Q, 0, 0), a01 = ARD(D, Q, 0, 1);                     \
    bf16x8 a10 = ARD(D, Q, 1, 0), a11 = ARD(D, Q, 1, 1);                     \
    if (DO_B) {                                                              \
      _Pragma("unroll") for (int ni = 0; ni < 4; ni++) {                     \
        bk0[ni] = BRD(D, ni, 0);                                             \
        bk1[ni] = BRD(D, ni, 1);                                             \
      }                                                                      \
    }                                                                        \
    STG_STMT;                                                                \
    WAIT_STMT;                                                               \
    __builtin_amdgcn_s_barrier();                                            \
    asm volatile("s_waitcnt lgkmcnt(0)" ::: "memory");                       \
    __builtin_amdgcn_sched_barrier(0);                                       \
    __builtin_amdgcn_s_setprio(1);                                           \
    _Pragma("unroll") for (int ni = 0; ni < 4; ni++) {                       \
      acc[(Q) * 2][ni] = MFMA16(a00, bk0[ni], acc[(Q) * 2][ni]);             \
      acc[(Q) * 2][ni] = MFMA16(a01, bk1[ni], acc[(Q) * 2][ni]);             \
      acc[(Q) * 2 + 1][ni] = MFMA16(a10, bk0[ni], acc[(Q) * 2 + 1][ni]);     \
      acc[(Q) * 2 + 1][ni] = MFMA16(a11, bk1[ni], acc[(Q) * 2 + 1][ni]);     \
    }                                                                        \
    __builtin_amdgcn_s_setprio(0);                                           \
    __builtin_amdgcn_s_barrier();                                            \
  }

// TILE: D = buf of tile T, DN = buf of tile T+2 ( = (T+2)%3 )
#define TILE(D, DN, T)                                                       \
  PHASE(D, 0, 1, { stg(1, DN, (T) + 2); stg(0, DN, (T) + 2); }, )            \
  PHASE(D, 1, 0, { stg(2, DN, (T) + 2); },                                   \
        if ((T) < 14) asm volatile("s_waitcnt vmcnt(6)" ::: "memory");       \
        else if ((T) == 14) asm volatile("s_waitcnt vmcnt(0)" ::: "memory"))

  // prologue: stage tile0 -> buf0, tile1 -> buf1; wait for tile0's 6 loads
  stg(1, 0, 0); stg(0, 0, 0); stg(2, 0, 0);
  stg(1, 1, 1); stg(0, 1, 1); stg(2, 1, 1);
  asm volatile("s_waitcnt vmcnt(6)" ::: "memory");
  __builtin_amdgcn_s_barrier();

#pragma unroll 1
  for (int I = 0; I < 5; ++I) {
    const int T0 = 3 * I;
    TILE(0, 2, T0)
    TILE(1, 0, T0 + 1)
    TILE(2, 1, T0 + 2)
  }
  TILE(0, 2, 15)
#undef TILE
#undef PHASE
#undef ARD
#undef BRD
#undef MFMA16

  // ---- fused epilogue (per-wave 64x64 at bm+wr*64, bn+wc*64) ----
  const int rb = bm + wr * 64 + quad * 4;
  const int cb = bn + wc * 64 + lcol;
  if (bn >= 2048) {
#pragma unroll
    for (int mi = 0; mi < 4; mi++) {
#pragma unroll
      for (int ni = 0; ni < 4; ni++) {
        int row0 = rb + mi * 16;
        int s = row0 & (Sn - 1);
        int bb = row0 >> 11;
        int vcol = cb + ni * 16 - 2048;
        int bh = (bb << 4) + (vcol >> 6);
        int hd = vcol & 63;
        unsigned d0 = (unsigned)f2bf(acc[mi][ni][0]) |
                      ((unsigned)f2bf(acc[mi][ni][1]) << 16);
        unsigned d1 = (unsigned)f2bf(acc[mi][ni][2]) |
                      ((unsigned)f2bf(acc[mi][ni][3]) << 16);
        *(uint2*)(vt + ((size_t)bh * HDn + hd) * Sn + s) = (uint2){d0, d1};
      }
    }
  } else {
    const float scale = (bn < 1024) ? qscale : 1.0f;
#pragma unroll
    for (int mi = 0; mi < 4; mi++) {
#pragma unroll
      for (int ni = 0; ni < 4; ni++) {
        int row0 = rb + mi * 16;
        int col = cb + ni * 16;
#pragma unroll
        for (int r = 0; r < 4; r++)
          qkb[(size_t)(row0 + r) * 2048 + col] = f2bf(acc[mi][ni][r] * scale);
      }
    }
  }
}

// ---- output gemm: [8192 x 1024] fp32+bias, 128x128 tile, BK=64, DBUF ----
__global__ __launch_bounds__(256) void gemm_out(const u16* __restrict__ A,
                                                const u16* __restrict__ Bt,
                                                float* __restrict__ Cout,
                                                const float* __restrict__ bias) {
  __shared__ __attribute__((aligned(16))) u16 As[2][2][128][32];
  __shared__ __attribute__((aligned(16))) u16 Bs[2][2][128][32];
  const int K = Dn;
  const int t = threadIdx.x;
  const int wave = t >> 6;
  const int lane = t & 63;
  const int lcol = lane & 15;
  const int quad = lane >> 4;
  const int wm = (wave >> 1) * 64;
  const int wn = (wave & 1) * 64;
  const int bm = blockIdx.y * 128;
  const int bn = blockIdx.x * 128;

  const int srow = lane >> 2;
  const int sseg = (lane & 3) * 8;
  const u16* a0p = A + (size_t)(bm + wave * 16 + srow) * K + sseg;
  const u16* a1p = a0p + (size_t)64 * K;
  const u16* b0p = Bt + (size_t)(bn + wave * 16 + srow) * K + sseg;
  const u16* b1p = b0p + (size_t)64 * K;
  u16* asl = &As[0][0][0][0] + wave * 512 + lane * 8;
  u16* bsl = &Bs[0][0][0][0] + wave * 512 + lane * 8;

  auto stage = [&](int k0, int d) {
    u16* as = asl + d * 8192;
    u16* bs = bsl + d * 8192;
    gl2lds16(a0p + k0, as);
    gl2lds16(a1p + k0, as + 2048);
    gl2lds16(a0p + k0 + 32, as + 4096);
    gl2lds16(a1p + k0 + 32, as + 6144);
    gl2lds16(b0p + k0, bs);
    gl2lds16(b1p + k0, bs + 2048);
    gl2lds16(b0p + k0 + 32, bs + 4096);
    gl2lds16(b1p + k0 + 32, bs + 6144);
  };

  f32x4 acc[4][4];
#pragma unroll
  for (int i = 0; i < 4; i++)
#pragma unroll
    for (int j = 0; j < 4; j++) acc[i][j] = (f32x4){0.f, 0.f, 0.f, 0.f};

  stage(0, 0);
  int d = 0;
  for (int k0 = 0; k0 < K; k0 += 64, d ^= 1) {
    __syncthreads();
    if (k0 + 64 < K) stage(k0 + 64, d ^ 1);
#pragma unroll
    for (int ks = 0; ks < 2; ks++) {
      bf16x8 af[4], bf[4];
#pragma unroll
      for (int mi = 0; mi < 4; mi++)
        af[mi] = *(const bf16x8*)(&As[d][ks][wm + mi * 16 + lcol][quad * 8]);
#pragma unroll
      for (int ni = 0; ni < 4; ni++)
        bf[ni] = *(const bf16x8*)(&Bs[d][ks][wn + ni * 16 + lcol][quad * 8]);
#pragma unroll
      for (int mi = 0; mi < 4; mi++)
#pragma unroll
        for (int ni = 0; ni < 4; ni++)
          acc[mi][ni] = __builtin_amdgcn_mfma_f32_16x16x32_bf16(af[mi], bf[ni], acc[mi][ni], 0, 0, 0);
    }
  }

#pragma unroll
  for (int mi = 0; mi < 4; mi++) {
#pragma unroll
    for (int ni = 0; ni < 4; ni++) {
#pragma unroll
      for (int r = 0; r < 4; r++) {
        int row = bm + wm + mi * 16 + quad * 4 + r;
        int col = bn + wn + ni * 16 + lcol;
        Cout[(size_t)row * Dn + col] = acc[mi][ni][r] + bias[col];
      }
    }
  }
}

// ---- causal flash attention v5: paired strips for uniform load ----
__global__ __launch_bounds__(256, 2) void attn5(const u16* __restrict__ QK,
                                                const u16* __restrict__ Vt,
                                                u16* __restrict__ ctx) {
  __shared__ __attribute__((aligned(16))) u16 Ks2[2][64][32];
  __shared__ __attribute__((aligned(16))) u16 Vts2[2][64][32];
  __shared__ __attribute__((aligned(16))) u16 Pt[4][32][72];

  const int bh = blockIdx.x;
  const int b = bh >> 4, h = bh & 15;
  const int pair = blockIdx.y;           // 0..7
  const int t = threadIdx.x;
  const int w = t >> 6;
  const int lane = t & 63;
  const int lcol = lane & 15;
  const int quad = lane >> 4;
  const int qw0 = pair * 128 + w * 32;          // short strip wave base
  const int qw1 = (15 - pair) * 128 + w * 32;   // long strip wave base

  const size_t qkbase = ((size_t)b * Sn) * 2048 + h * HDn;
  const size_t obase = ((size_t)b * Sn) * Dn + h * HDn;
  const size_t vbase = ((size_t)bh * HDn) * Sn;

  bf16x8 qf[2][2][2];  // [strip][qb][kc]
#pragma unroll
  for (int si = 0; si < 2; si++) {
    const int qws = si ? qw1 : qw0;
#pragma unroll
    for (int qb = 0; qb < 2; qb++) {
      const u16* qp = QK + qkbase + (size_t)(qws + qb * 16 + lcol) * 2048 + quad * 8;
      qf[si][qb][0] = *(const bf16x8*)qp;
      qf[si][qb][1] = *(const bf16x8*)(qp + 32);
    }
  }

  f32x4 o[2][2][4];  // [strip][qb][nb]
#pragma unroll
  for (int si = 0; si < 2; si++)
#pragma unroll
    for (int qb = 0; qb < 2; qb++)
#pragma unroll
      for (int nb = 0; nb < 4; nb++) o[si][qb][nb] = (f32x4){0.f, 0.f, 0.f, 0.f};
  float lsum[2][2] = {{0.f, 0.f}, {0.f, 0.f}};

  const int srow = lane >> 2;
  const int sseg = (lane & 3) * 8;
  const u16* kp0 = QK + qkbase + 1024 + (size_t)(w * 16 + srow) * 2048 + sseg;
  const u16* vp0 = Vt + vbase + (size_t)(w * 16 + srow) * Sn + sseg;
  u16* ksl0 = &Ks2[0][0][0] + w * 512 + lane * 8;
  u16* ksl1 = ksl0 + 2048;
  u16* vsl0 = &Vts2[0][0][0] + w * 512 + lane * 8;
  u16* vsl1 = vsl0 + 2048;

  auto do_strip = [&](int si, int qw, int j0) {
    f32x4 s[4][2];
#pragma unroll
    for (int mb = 0; mb < 4; mb++) {
      bf16x8 kf0 = *(const bf16x8*)(&Ks2[0][mb * 16 + lcol][quad * 8]);
      bf16x8 kf1 = *(const bf16x8*)(&Ks2[1][mb * 16 + lcol][quad * 8]);
#pragma unroll
      for (int qb = 0; qb < 2; qb++) {
        f32x4 a = (f32x4){0.f, 0.f, 0.f, 0.f};
        a = __builtin_amdgcn_mfma_f32_16x16x32_bf16(kf0, qf[si][qb][0], a, 0, 0, 0);
        a = __builtin_amdgcn_mfma_f32_16x16x32_bf16(kf1, qf[si][qb][1], a, 0, 0, 0);
        s[mb][qb] = a;
      }
    }

    const bool needmask = (j0 + 63 > qw);
#pragma unroll
    for (int qb = 0; qb < 2; qb++) {
      const int qrow = qw + qb * 16 + lcol;
#pragma unroll
      for (int mb = 0; mb < 4; mb++) {
        float p[4];
#pragma unroll
        for (int r = 0; r < 4; r++) p[r] = fexp2(s[mb][qb][r]);
        if (needmask) {
          const int kvb = j0 + mb * 16 + quad * 4;
#pragma unroll
          for (int r = 0; r < 4; r++)
            if (kvb + r > qrow) p[r] = 0.f;
        }
        lsum[si][qb] += (p[0] + p[1]) + (p[2] + p[3]);
        unsigned d0 = pk_bf_trunc(p[0], p[1]);
        unsigned d1 = pk_bf_trunc(p[2], p[3]);
        *(uint2*)(&Pt[w][qb * 16 + lcol][mb * 16 + quad * 4]) = (uint2){d0, d1};
      }
    }

#pragma unroll
    for (int c = 0; c < 2; c++) {
      bf16x8 pf0 = *(const bf16x8*)(&Pt[w][lcol][c * 32 + quad * 8]);
      bf16x8 pf1 = *(const bf16x8*)(&Pt[w][16 + lcol][c * 32 + quad * 8]);
#pragma unroll
      for (int nb = 0; nb < 4; nb++) {
        bf16x8 vf = *(const bf16x8*)(&Vts2[c][nb * 16 + lcol][quad * 8]);
        o[si][0][nb] = __builtin_amdgcn_mfma_f32_16x16x32_bf16(vf, pf0, o[si][0][nb], 0, 0, 0);
        o[si][1][nb] = __builtin_amdgcn_mfma_f32_16x16x32_bf16(vf, pf1, o[si][1][nb], 0, 0, 0);
      }
    }
  };

  const int n_kv = (15 - pair) * 128 + 128;  // long strip upper bound

  for (int j0 = 0; j0 < n_kv; j0 += 64) {
    {
      const u16* kp = kp0 + (size_t)j0 * 2048;
      gl2lds16(kp, ksl0);
      gl2lds16(kp + 32, ksl1);
      const u16* vp = vp0 + j0;
      gl2lds16(vp, vsl0);
      gl2lds16(vp + 32, vsl1);
    }
    __syncthreads();

    if (j0 <= qw1 + 31) do_strip(1, qw1, j0);  // long strip
    if (j0 <= qw0 + 31) do_strip(0, qw0, j0);  // short strip
    __syncthreads();
  }

#pragma unroll
  for (int si = 0; si < 2; si++) {
    const int qws = si ? qw1 : qw0;
#pragma unroll
    for (int qb = 0; qb < 2; qb++) {
      float l = lsum[si][qb];
      l += __shfl_xor(l, 16);
      l += __shfl_xor(l, 32);
      float inv = 1.0f / l;
#pragma unroll
      for (int nb = 0; nb < 4; nb++) {
        unsigned d0 = (unsigned)f2bf(o[si][qb][nb][0] * inv) |
                      ((unsigned)f2bf(o[si][qb][nb][1] * inv) << 16);
        unsigned d1 = (unsigned)f2bf(o[si][qb][nb][2] * inv) |
                      ((unsigned)f2bf(o[si][qb][nb][3] * inv) << 16);
        u16* p = ctx + obase + (size_t)(qws + qb * 16 + lcol) * Dn + nb * 16 + quad * 4;
        *(uint2*)p = (uint2){d0, d1};
      }
    }
  }
}

extern "C" void kernel_launch(void* const* d_in, const int* in_sizes, int n_in,
                              void* d_out, int out_size, void* d_ws, size_t ws_size,
                              hipStream_t stream) {
  const float* x  = (const float*)d_in[0];
  const float* Wq = (const float*)d_in[1];
  const float* Wk = (const float*)d_in[2];
  const float* Wv = (const float*)d_in[3];
  const float* Wo = (const float*)d_in[4];
  const float* bo = (const float*)d_in[5];
  float* out = (float*)d_out;

  const size_t BSD = (size_t)Bn * Sn * Dn;
  const size_t DD = (size_t)Dn * Dn;

  u16* xb    = (u16*)d_ws;           // BSD
  u16* wall  = xb + BSD;             // 4*DD  (Wq^T, Wk^T, Wv^T, Wo^T)
  u16* qkb   = wall + 4 * DD;        // 2*BSD
  u16* vt    = qkb + 2 * BSD;        // BSD
  u16* cb    = vt + BSD;             // BSD

  cvt4<<<(int)(BSD / 4 / 256), 256, 0, stream>>>(x, xb, (int)(BSD / 4));
  tcvt4<<<dim3(Dn / 32, Dn / 32, 4), 256, 0, stream>>>(Wq, Wk, Wv, Wo, wall);

  // fused QKV projection: 128x256 tiles, triple-buffer, 768 blocks (3 rounds)
  gemm_qkv<<<dim3(768), 512, 0, stream>>>(xb, wall, qkb, vt,
                                          0.125f * 1.44269504f);

  attn5<<<dim3(Bn * Hn, 8), 256, 0, stream>>>(qkb, vt, cb);

  // output projection: 128x128 tiles, 512 blocks, dbuf DMA
  gemm_out<<<dim3(Dn / 128, (Bn * Sn) / 128), 256, 0, stream>>>(cb, wall + 3 * DD, out, bo);
}

// Round 5
// 225.346 us; speedup vs baseline: 1.0982x; 1.0982x over previous
//
#include <hip/hip_runtime.h>

typedef unsigned short u16;
typedef __bf16 bf16x8 __attribute__((ext_vector_type(8)));
typedef float f32x4 __attribute__((ext_vector_type(4)));

#define Bn 4
#define Sn 2048
#define Dn 1024
#define Hn 16
#define HDn 64

__device__ inline u16 f2bf(float f) {
  unsigned u = __builtin_bit_cast(unsigned, f);
  u += 0x7fffu + ((u >> 16) & 1u);
  return (u16)(u >> 16);
}

// async global->LDS DMA, 16B/lane; LDS dest = wave base + lane*16 [m97]
__device__ __forceinline__ void gl2lds16(const u16* g, u16* l) {
  __builtin_amdgcn_global_load_lds(
      (const __attribute__((address_space(1))) unsigned int*)g,
      (__attribute__((address_space(3))) unsigned int*)l, 16, 0, 0);
}

__device__ __forceinline__ float fexp2(float x) {
  return __builtin_amdgcn_exp2f(x);
}

// pack two f32 -> two bf16 (truncating) in one v_perm
__device__ __forceinline__ unsigned pk_bf_trunc(float lo, float hi) {
  return __builtin_amdgcn_perm(__builtin_bit_cast(unsigned, hi),
                               __builtin_bit_cast(unsigned, lo), 0x07060302u);
}

// ---- elementwise fp32 -> bf16 convert (x) ----
__global__ __launch_bounds__(256) void cvt4(const float* __restrict__ in,
                                            u16* __restrict__ out, int n4) {
  int i = blockIdx.x * 256 + threadIdx.x;
  if (i < n4) {
    float4 v = ((const float4*)in)[i];
    ushort4 o;
    o.x = f2bf(v.x); o.y = f2bf(v.y); o.z = f2bf(v.z); o.w = f2bf(v.w);
    ((ushort4*)out)[i] = o;
  }
}

// ---- transpose + convert 4 weights in one launch: out[z][n][k] = in_z[k][n] ----
__global__ __launch_bounds__(256) void tcvt4(const float* __restrict__ w0,
                                             const float* __restrict__ w1,
                                             const float* __restrict__ w2,
                                             const float* __restrict__ w3,
                                             u16* __restrict__ out) {
  __shared__ u16 tile[32][33];
  const float* in = (blockIdx.z == 0) ? w0 : (blockIdx.z == 1) ? w1
                   : (blockIdx.z == 2) ? w2 : w3;
  u16* dst = out + (size_t)blockIdx.z * Dn * Dn;
  int bx = blockIdx.x * 32;
  int by = blockIdx.y * 32;
  int tx = threadIdx.x & 31;
  int ty = threadIdx.x >> 5;
#pragma unroll
  for (int r = 0; r < 32; r += 8)
    tile[ty + r][tx] = f2bf(in[(size_t)(by + ty + r) * Dn + bx + tx]);
  __syncthreads();
#pragma unroll
  for (int r = 0; r < 32; r += 8)
    dst[(size_t)(bx + ty + r) * Dn + by + tx] = tile[tx][ty + r];
}

// ==== shared 128x256 / BK=64 / triple-buffer / 1-barrier-per-tile K-loop ====
// 512 threads = 8 waves in 2(M) x 4(N); per-wave output 64x64 (acc[4][4]).
// LDS 3 bufs x 3 regions x 16KB = 144KB:
//   rg0: A rows 0..127 ; rg1: B rows {wc*64+0..31} ; rg2: B rows {wc*64+32..63}
// Per K-tile (ONE barrier): stage tile T+2 -> buf (T+2)%3 (6 gl2lds);
// ds_read all 16 frags of tile T; lgkmcnt(0)+sched_barrier; 32 MFMA
// (k-step0 x16 independent, then k-step1 x16); vmcnt(6); s_barrier.
// Cross-wave skew inside the tile lets other waves' MFMA cover the LDS
// drain (vs R4's 4-barrier lockstep that serialized LDS vs MFMA).
// vmcnt ledger (unchanged from R4, proven): at tile T's wait, outstanding =
// 12 (T+1's 6 + T+2's 6); vmcnt(6) retires exactly T+1's. Write-after-read
// on buf (T+2)%3: its last reads (tile T-1) drained at T-1's lgkmcnt(0)
// before T-1's closing barrier, which precedes tile T's stage. vmcnt(0)
// only at T=14 (covers T15; T16/17 stages are guarded out).
// LDS swizzle: physical = logical ^ ((row bits1-3)<<4); gl2lds dest linear,
// global source inverse-swizzled (rule #21); ds_read same involution ->
// conflict-free (SQ_LDS_BANK_CONFLICT == 0 verified R1/R2/R4).
#define MFMA16(a, b, c) __builtin_amdgcn_mfma_f32_16x16x32_bf16(a, b, c, 0, 0, 0)

#define SRCP_INIT(APTR, BPTR)                                                \
  const u16* srcp[3][2];                                                     \
  _Pragma("unroll") for (int rg = 0; rg < 3; rg++) {                         \
    _Pragma("unroll") for (int j = 0; j < 2; j++) {                          \
      int o = j * 8192 + tid * 16;                                           \
      int l = o ^ (((o >> 8) & 7) << 4);                                     \
      int rho = l >> 7;                                                      \
      int c2 = (l >> 1) & 63;                                                \
      int gr;                                                                \
      if (rg == 0)      gr = bm + rho;                                       \
      else if (rg == 1) gr = bn + ((rho >> 5) << 6) + (rho & 31);            \
      else              gr = bn + ((rho >> 5) << 6) + 32 + (rho & 31);       \
      const u16* base = (rg == 0) ? (APTR) : (BPTR);                         \
      srcp[rg][j] = base + (size_t)gr * Dn + c2;                             \
    }                                                                        \
  }

// A frag: half Q (0..1), F = frag-in-half (0..1), K = k-step
#define ARD(D, Q, F, K)                                                      \
  (*(const bf16x8*)((const char*)&S[D][0][0] +                               \
      ((wr * 64 + (Q) * 32 + (F) * 16 + lcol) * 128 + ((K) ? cs1 : cs0))))
// B frag: NI = N-frag (0..3), K = k-step
#define BRD(D, NI, K)                                                        \
  (*(const bf16x8*)((const char*)&S[D][1 + ((NI) >> 1)][0] +                 \
      ((wc * 32 + ((NI) & 1) * 16 + lcol) * 128 + ((K) ? cs1 : cs0))))

#define VM6 asm volatile("s_waitcnt vmcnt(6)" ::: "memory")
#define VM0 asm volatile("s_waitcnt vmcnt(0)" ::: "memory")

#define KTILE(D, DN, T, WAIT)                                                \
  {                                                                          \
    stg(0, DN, (T) + 2); stg(1, DN, (T) + 2); stg(2, DN, (T) + 2);           \
    bf16x8 a00 = ARD(D, 0, 0, 0), a01 = ARD(D, 0, 0, 1);                     \
    bf16x8 a10 = ARD(D, 0, 1, 0), a11 = ARD(D, 0, 1, 1);                     \
    bf16x8 a20 = ARD(D, 1, 0, 0), a21 = ARD(D, 1, 0, 1);                     \
    bf16x8 a30 = ARD(D, 1, 1, 0), a31 = ARD(D, 1, 1, 1);                     \
    bf16x8 bk0[4], bk1[4];                                                   \
    _Pragma("unroll") for (int ni = 0; ni < 4; ni++) {                       \
      bk0[ni] = BRD(D, ni, 0); bk1[ni] = BRD(D, ni, 1);                      \
    }                                                                        \
    asm volatile("s_waitcnt lgkmcnt(0)" ::: "memory");                       \
    __builtin_amdgcn_sched_barrier(0);                                       \
    __builtin_amdgcn_s_setprio(1);                                           \
    _Pragma("unroll") for (int ni = 0; ni < 4; ni++) {                       \
      acc[0][ni] = MFMA16(a00, bk0[ni], acc[0][ni]);                         \
      acc[1][ni] = MFMA16(a10, bk0[ni], acc[1][ni]);                         \
      acc[2][ni] = MFMA16(a20, bk0[ni], acc[2][ni]);                         \
      acc[3][ni] = MFMA16(a30, bk0[ni], acc[3][ni]);                         \
    }                                                                        \
    _Pragma("unroll") for (int ni = 0; ni < 4; ni++) {                       \
      acc[0][ni] = MFMA16(a01, bk1[ni], acc[0][ni]);                         \
      acc[1][ni] = MFMA16(a11, bk1[ni], acc[1][ni]);                         \
      acc[2][ni] = MFMA16(a21, bk1[ni], acc[2][ni]);                         \
      acc[3][ni] = MFMA16(a31, bk1[ni], acc[3][ni]);                         \
    }                                                                        \
    __builtin_amdgcn_s_setprio(0);                                           \
    WAIT;                                                                    \
    __builtin_amdgcn_s_barrier();                                            \
    __builtin_amdgcn_sched_barrier(0);                                       \
  }

#define KLOOP                                                                \
  stg(0, 0, 0); stg(1, 0, 0); stg(2, 0, 0);                                  \
  stg(0, 1, 1); stg(1, 1, 1); stg(2, 1, 1);                                  \
  VM6;                                                                       \
  __builtin_amdgcn_s_barrier();                                              \
  __builtin_amdgcn_sched_barrier(0);                                         \
  _Pragma("unroll 1") for (int I = 0; I < 5; ++I) {                          \
    const int T0 = 3 * I;                                                    \
    KTILE(0, 2, T0, VM6)                                                     \
    KTILE(1, 0, T0 + 1, VM6)                                                 \
    KTILE(2, 1, T0 + 2, if (I == 4) { VM0; } else { VM6; })                  \
  }                                                                          \
  KTILE(0, 2, 15, )

// ==== fused QKV gemm: M=8192, N=3072 (Q|K|V), K=1024; 768 blocks = 3 rounds
__global__ __launch_bounds__(512, 2) void gemm_qkv(const u16* __restrict__ A,
                                                   const u16* __restrict__ Bt,
                                                   u16* __restrict__ qkb,
                                                   u16* __restrict__ vt,
                                                   float qscale) {
  __shared__ __attribute__((aligned(16))) u16 S[3][3][8192];  // 144 KB

  const int tid = threadIdx.x;
  const int lane = tid & 63;
  const int lcol = lane & 15;
  const int quad = lane >> 4;
  const int wave = tid >> 6;
  const int wr = wave >> 2;  // 0..1 (M)
  const int wc = wave & 3;   // 0..3 (N)

  // XCD swizzle: xcd = bid&7 owns M-tiles xcd*8..+7 across all 12 N-tiles.
  const int bid = blockIdx.x;
  const int idx = bid >> 3;                             // 0..95
  const int bm = (((bid & 7) << 3) + (idx & 7)) * 128;  // M tile 0..63
  const int bn = (idx >> 3) * 256;                      // N tile 0..11

  SRCP_INIT(A, Bt)

  auto stg = [&](int rg, int buf, int tile) {
    if (tile >= 16) return;  // tail guard (tiles 16,17)
    const int k0 = tile << 6;
    u16* d = &S[buf][rg][tid * 8];
    gl2lds16(srcp[rg][0] + k0, d);
    gl2lds16(srcp[rg][1] + k0, d + 4096);
  };

  f32x4 acc[4][4];
#pragma unroll
  for (int i = 0; i < 4; i++)
#pragma unroll
    for (int j = 0; j < 4; j++) acc[i][j] = (f32x4){0.f, 0.f, 0.f, 0.f};

  const int SW = (lcol & 14) << 3;
  const int cs0 = (quad * 16) ^ SW;
  const int cs1 = (64 + quad * 16) ^ SW;

  KLOOP

  // ---- fused epilogue (per-wave 64x64 at bm+wr*64, bn+wc*64) ----
  const int rb = bm + wr * 64 + quad * 4;
  const int cb = bn + wc * 64 + lcol;
  if (bn >= 2048) {
#pragma unroll
    for (int mi = 0; mi < 4; mi++) {
#pragma unroll
      for (int ni = 0; ni < 4; ni++) {
        int row0 = rb + mi * 16;
        int s = row0 & (Sn - 1);
        int bb = row0 >> 11;
        int vcol = cb + ni * 16 - 2048;
        int bh = (bb << 4) + (vcol >> 6);
        int hd = vcol & 63;
        unsigned d0 = (unsigned)f2bf(acc[mi][ni][0]) |
                      ((unsigned)f2bf(acc[mi][ni][1]) << 16);
        unsigned d1 = (unsigned)f2bf(acc[mi][ni][2]) |
                      ((unsigned)f2bf(acc[mi][ni][3]) << 16);
        *(uint2*)(vt + ((size_t)bh * HDn + hd) * Sn + s) = (uint2){d0, d1};
      }
    }
  } else {
    const float scale = (bn < 1024) ? qscale : 1.0f;
#pragma unroll
    for (int mi = 0; mi < 4; mi++) {
#pragma unroll
      for (int ni = 0; ni < 4; ni++) {
        int row0 = rb + mi * 16;
        int col = cb + ni * 16;
#pragma unroll
        for (int r = 0; r < 4; r++)
          qkb[(size_t)(row0 + r) * 2048 + col] = f2bf(acc[mi][ni][r] * scale);
      }
    }
  }
}

// ==== output gemm: M=8192, N=1024, K=1024; 256 blocks = 1 perfect round ====
__global__ __launch_bounds__(512, 2) void gemm_out(const u16* __restrict__ A,
                                                   const u16* __restrict__ Bt,
                                                   float* __restrict__ Cout,
                                                   const float* __restrict__ bias) {
  __shared__ __attribute__((aligned(16))) u16 S[3][3][8192];  // 144 KB

  const int tid = threadIdx.x;
  const int lane = tid & 63;
  const int lcol = lane & 15;
  const int quad = lane >> 4;
  const int wave = tid >> 6;
  const int wr = wave >> 2;  // 0..1 (M)
  const int wc = wave & 3;   // 0..3 (N)

  // 256 blocks: xcd = bid&7 owns 8 M-tiles x 4 N-tiles (A 2MB + B 2MB L2-fit)
  const int bid = blockIdx.x;
  const int idx = bid >> 3;                             // 0..31
  const int bm = (((bid & 7) << 3) + (idx & 7)) * 128;  // M tile 0..63
  const int bn = (idx >> 3) * 256;                      // N tile 0..3

  SRCP_INIT(A, Bt)

  auto stg = [&](int rg, int buf, int tile) {
    if (tile >= 16) return;
    const int k0 = tile << 6;
    u16* d = &S[buf][rg][tid * 8];
    gl2lds16(srcp[rg][0] + k0, d);
    gl2lds16(srcp[rg][1] + k0, d + 4096);
  };

  f32x4 acc[4][4];
#pragma unroll
  for (int i = 0; i < 4; i++)
#pragma unroll
    for (int j = 0; j < 4; j++) acc[i][j] = (f32x4){0.f, 0.f, 0.f, 0.f};

  const int SW = (lcol & 14) << 3;
  const int cs0 = (quad * 16) ^ SW;
  const int cs1 = (64 + quad * 16) ^ SW;

  KLOOP

  // ---- epilogue: fp32 + bias ----
  const int rb = bm + wr * 64 + quad * 4;
  const int cb = bn + wc * 64 + lcol;
  float bv[4];
#pragma unroll
  for (int ni = 0; ni < 4; ni++) bv[ni] = bias[cb + ni * 16];
#pragma unroll
  for (int mi = 0; mi < 4; mi++) {
#pragma unroll
    for (int ni = 0; ni < 4; ni++) {
      int row0 = rb + mi * 16;
      int col = cb + ni * 16;
#pragma unroll
      for (int r = 0; r < 4; r++)
        Cout[(size_t)(row0 + r) * Dn + col] = acc[mi][ni][r] + bv[ni];
    }
  }
}

// ---- causal flash attention v5: paired strips for uniform load ----
__global__ __launch_bounds__(256, 2) void attn5(const u16* __restrict__ QK,
                                                const u16* __restrict__ Vt,
                                                u16* __restrict__ ctx) {
  __shared__ __attribute__((aligned(16))) u16 Ks2[2][64][32];
  __shared__ __attribute__((aligned(16))) u16 Vts2[2][64][32];
  __shared__ __attribute__((aligned(16))) u16 Pt[4][32][72];

  const int bh = blockIdx.x;
  const int b = bh >> 4, h = bh & 15;
  const int pair = blockIdx.y;           // 0..7
  const int t = threadIdx.x;
  const int w = t >> 6;
  const int lane = t & 63;
  const int lcol = lane & 15;
  const int quad = lane >> 4;
  const int qw0 = pair * 128 + w * 32;          // short strip wave base
  const int qw1 = (15 - pair) * 128 + w * 32;   // long strip wave base

  const size_t qkbase = ((size_t)b * Sn) * 2048 + h * HDn;
  const size_t obase = ((size_t)b * Sn) * Dn + h * HDn;
  const size_t vbase = ((size_t)bh * HDn) * Sn;

  bf16x8 qf[2][2][2];  // [strip][qb][kc]
#pragma unroll
  for (int si = 0; si < 2; si++) {
    const int qws = si ? qw1 : qw0;
#pragma unroll
    for (int qb = 0; qb < 2; qb++) {
      const u16* qp = QK + qkbase + (size_t)(qws + qb * 16 + lcol) * 2048 + quad * 8;
      qf[si][qb][0] = *(const bf16x8*)qp;
      qf[si][qb][1] = *(const bf16x8*)(qp + 32);
    }
  }

  f32x4 o[2][2][4];  // [strip][qb][nb]
#pragma unroll
  for (int si = 0; si < 2; si++)
#pragma unroll
    for (int qb = 0; qb < 2; qb++)
#pragma unroll
      for (int nb = 0; nb < 4; nb++) o[si][qb][nb] = (f32x4){0.f, 0.f, 0.f, 0.f};
  float lsum[2][2] = {{0.f, 0.f}, {0.f, 0.f}};

  const int srow = lane >> 2;
  const int sseg = (lane & 3) * 8;
  const u16* kp0 = QK + qkbase + 1024 + (size_t)(w * 16 + srow) * 2048 + sseg;
  const u16* vp0 = Vt + vbase + (size_t)(w * 16 + srow) * Sn + sseg;
  u16* ksl0 = &Ks2[0][0][0] + w * 512 + lane * 8;
  u16* ksl1 = ksl0 + 2048;
  u16* vsl0 = &Vts2[0][0][0] + w * 512 + lane * 8;
  u16* vsl1 = vsl0 + 2048;

  auto do_strip = [&](int si, int qw, int j0) {
    f32x4 s[4][2];
#pragma unroll
    for (int mb = 0; mb < 4; mb++) {
      bf16x8 kf0 = *(const bf16x8*)(&Ks2[0][mb * 16 + lcol][quad * 8]);
      bf16x8 kf1 = *(const bf16x8*)(&Ks2[1][mb * 16 + lcol][quad * 8]);
#pragma unroll
      for (int qb = 0; qb < 2; qb++) {
        f32x4 a = (f32x4){0.f, 0.f, 0.f, 0.f};
        a = __builtin_amdgcn_mfma_f32_16x16x32_bf16(kf0, qf[si][qb][0], a, 0, 0, 0);
        a = __builtin_amdgcn_mfma_f32_16x16x32_bf16(kf1, qf[si][qb][1], a, 0, 0, 0);
        s[mb][qb] = a;
      }
    }

    const bool needmask = (j0 + 63 > qw);
#pragma unroll
    for (int qb = 0; qb < 2; qb++) {
      const int qrow = qw + qb * 16 + lcol;
#pragma unroll
      for (int mb = 0; mb < 4; mb++) {
        float p[4];
#pragma unroll
        for (int r = 0; r < 4; r++) p[r] = fexp2(s[mb][qb][r]);
        if (needmask) {
          const int kvb = j0 + mb * 16 + quad * 4;
#pragma unroll
          for (int r = 0; r < 4; r++)
            if (kvb + r > qrow) p[r] = 0.f;
        }
        lsum[si][qb] += (p[0] + p[1]) + (p[2] + p[3]);
        unsigned d0 = pk_bf_trunc(p[0], p[1]);
        unsigned d1 = pk_bf_trunc(p[2], p[3]);
        *(uint2*)(&Pt[w][qb * 16 + lcol][mb * 16 + quad * 4]) = (uint2){d0, d1};
      }
    }

#pragma unroll
    for (int c = 0; c < 2; c++) {
      bf16x8 pf0 = *(const bf16x8*)(&Pt[w][lcol][c * 32 + quad * 8]);
      bf16x8 pf1 = *(const bf16x8*)(&Pt[w][16 + lcol][c * 32 + quad * 8]);
#pragma unroll
      for (int nb = 0; nb < 4; nb++) {
        bf16x8 vf = *(const bf16x8*)(&Vts2[c][nb * 16 + lcol][quad * 8]);
        o[si][0][nb] = __builtin_amdgcn_mfma_f32_16x16x32_bf16(vf, pf0, o[si][0][nb], 0, 0, 0);
        o[si][1][nb] = __builtin_amdgcn_mfma_f32_16x16x32_bf16(vf, pf1, o[si][1][nb], 0, 0, 0);
      }
    }
  };

  const int n_kv = (15 - pair) * 128 + 128;  // long strip upper bound

  for (int j0 = 0; j0 < n_kv; j0 += 64) {
    {
      const u16* kp = kp0 + (size_t)j0 * 2048;
      gl2lds16(kp, ksl0);
      gl2lds16(kp + 32, ksl1);
      const u16* vp = vp0 + j0;
      gl2lds16(vp, vsl0);
      gl2lds16(vp + 32, vsl1);
    }
    __syncthreads();

    if (j0 <= qw1 + 31) do_strip(1, qw1, j0);  // long strip
    if (j0 <= qw0 + 31) do_strip(0, qw0, j0);  // short strip
    __syncthreads();
  }

#pragma unroll
  for (int si = 0; si < 2; si++) {
    const int qws = si ? qw1 : qw0;
#pragma unroll
    for (int qb = 0; qb < 2; qb++) {
      float l = lsum[si][qb];
      l += __shfl_xor(l, 16);
      l += __shfl_xor(l, 32);
      float inv = 1.0f / l;
#pragma unroll
      for (int nb = 0; nb < 4; nb++) {
        unsigned d0 = (unsigned)f2bf(o[si][qb][nb][0] * inv) |
                      ((unsigned)f2bf(o[si][qb][nb][1] * inv) << 16);
        unsigned d1 = (unsigned)f2bf(o[si][qb][nb][2] * inv) |
                      ((unsigned)f2bf(o[si][qb][nb][3] * inv) << 16);
        u16* p = ctx + obase + (size_t)(qws + qb * 16 + lcol) * Dn + nb * 16 + quad * 4;
        *(uint2*)p = (uint2){d0, d1};
      }
    }
  }
}

extern "C" void kernel_launch(void* const* d_in, const int* in_sizes, int n_in,
                              void* d_out, int out_size, void* d_ws, size_t ws_size,
                              hipStream_t stream) {
  const float* x  = (const float*)d_in[0];
  const float* Wq = (const float*)d_in[1];
  const float* Wk = (const float*)d_in[2];
  const float* Wv = (const float*)d_in[3];
  const float* Wo = (const float*)d_in[4];
  const float* bo = (const float*)d_in[5];
  float* out = (float*)d_out;

  const size_t BSD = (size_t)Bn * Sn * Dn;
  const size_t DD = (size_t)Dn * Dn;

  u16* xb    = (u16*)d_ws;           // BSD
  u16* wall  = xb + BSD;             // 4*DD  (Wq^T, Wk^T, Wv^T, Wo^T)
  u16* qkb   = wall + 4 * DD;        // 2*BSD
  u16* vt    = qkb + 2 * BSD;        // BSD
  u16* cb    = vt + BSD;             // BSD

  cvt4<<<(int)(BSD / 4 / 256), 256, 0, stream>>>(x, xb, (int)(BSD / 4));
  tcvt4<<<dim3(Dn / 32, Dn / 32, 4), 256, 0, stream>>>(Wq, Wk, Wv, Wo, wall);

  // fused QKV projection: 128x256 tiles, 1-barrier/tile, 768 blocks (3 rounds)
  gemm_qkv<<<dim3(768), 512, 0, stream>>>(xb, wall, qkb, vt,
                                          0.125f * 1.44269504f);

  attn5<<<dim3(Bn * Hn, 8), 256, 0, stream>>>(qkb, vt, cb);

  // output projection: 128x256 tiles, 256 blocks (1 perfect round)
  gemm_out<<<dim3(256), 512, 0, stream>>>(cb, wall + 3 * DD, out, bo);
}